// Round 11
// baseline (264.176 us; speedup 1.0000x reference)
//
#include <hip/hip_runtime.h>
#include <hip/hip_bf16.h>
#include <stdint.h>

#define NROWS 16384            // 16*32*32 flattened rows
#define KCODES 8192
#define DIM 256
#define HW 1024                // 32*32
#define CHW (DIM*HW)           // 262144
#define IDX_OFF 4194304        // 16*256*32*32
#define LOSS_OFF 4210688       // IDX_OFF + 16384
#define TAU 1.2e-4f            // candidate margin: grid(3.05e-5) + 2*bf16 tail + safety
#define SB_EPS 6e-5f           // bf16 storage slack for 16-group mins (|mn| <= ~0.024)

typedef unsigned long long u64;
typedef unsigned int u32;
typedef unsigned short ushort_t;

using frag = __attribute__((ext_vector_type(8))) short;   // 8 bf16 (4 VGPRs)
using accf = __attribute__((ext_vector_type(4))) float;   // 4 fp32 acc

__device__ __forceinline__ u32 forder(float f) {
    u32 u = __float_as_uint(f);
    return (u & 0x80000000u) ? ~u : (u | 0x80000000u);
}
__device__ __forceinline__ float unforder(u32 v) {
    u32 u = (v & 0x80000000u) ? (v ^ 0x80000000u) : ~v;
    return __uint_as_float(u);
}
__device__ __forceinline__ ushort_t bf16bits(float v) {
    __hip_bfloat16 t = __float2bfloat16(v);   // RNE
    return *reinterpret_cast<ushort_t*>(&t);
}
__device__ __forceinline__ float bflo(u32 u) { return __uint_as_float(u << 16); }
__device__ __forceinline__ float bfhi(u32 u) { return __uint_as_float(u & 0xFFFF0000u); }
__device__ __forceinline__ void async_cp16(const uint4* gp, uint4* lp) {
    __builtin_amdgcn_global_load_lds(
        (const __attribute__((address_space(1))) unsigned int*)gp,
        (__attribute__((address_space(3))) unsigned int*)lp, 16, 0, 0);
}

// max across each 16-lane DPP row, all on the VALU pipe (no DS traffic).
__device__ __forceinline__ float max_dpp16(float v) {
    int x;
    x = __builtin_amdgcn_update_dpp(__float_as_int(v), __float_as_int(v), 0xB1, 0xF, 0xF, true);
    v = fmaxf(v, __int_as_float(x));
    x = __builtin_amdgcn_update_dpp(__float_as_int(v), __float_as_int(v), 0x4E, 0xF, 0xF, true);
    v = fmaxf(v, __int_as_float(x));
    x = __builtin_amdgcn_update_dpp(__float_as_int(v), __float_as_int(v), 0x124, 0xF, 0xF, true);
    v = fmaxf(v, __int_as_float(x));
    x = __builtin_amdgcn_update_dpp(__float_as_int(v), __float_as_int(v), 0x128, 0xF, 0xF, true);
    v = fmaxf(v, __int_as_float(x));
    return v;
}

// EXACT scoring chain (bit-identical to all passing rounds): sequential k fp32
// fmaf on fp32 cb, fl32(rn - 2*dot), key = (ordered score, code); ties -> lowest.
__device__ __forceinline__ u64 exact_key(const float* __restrict__ cb,
                                         const float* __restrict__ fs,
                                         float rn_row, int code) {
    const float4* e4 = reinterpret_cast<const float4*>(&cb[(size_t)code << 8]);
    float acc = 0.0f;
    #pragma unroll 16
    for (int kk = 0; kk < 64; ++kk) {
        float4 ev = e4[kk];
        float4 fv = *reinterpret_cast<const float4*>(&fs[kk << 2]);
        acc = fmaf(fv.x, ev.x, acc);
        acc = fmaf(fv.y, ev.y, acc);
        acc = fmaf(fv.z, ev.z, acc);
        acc = fmaf(fv.w, ev.w, acc);
    }
    float s = __fadd_rn(rn_row, -2.0f * acc);
    return ((u64)forder(s) << 32) | (u64)code;
}

// ws layout (bytes):
//   keys     u64[16384]        @ 0        (131072)
//   rn       f32[16384]        @ 131072   (65536)
//   rowmin   u32[16384]        @ 196608   (65536)
//   A_bf     u16[16384*256]    @ 262144   (8388608)  PLANE-MAJOR+SWIZZLED:
//            uint4 idx = g*131072 + row*8 + ((u&7)^(row&7)), g=k-group(64k), u=k/8
//   B_bf     u16[8192*256]     @ 8650752  (4194304)  uint4 idx = g*65536 + code*8 + slot,
//            slot = u ^ (code&7)
//   sbmin16b u16[16384*512]    @ 12845056 (16777216) bf16 per (row, 16-code group)
//            approx min; group g = by*8 + wc*4 + ct <-> codes [g*16, g*16+16)
//   rowsT    f32[16384*256]    @ 29622272 (16777216) row-major exact fp32 hs rows

// hs -> bf16 rows (plane-major swizzled) + rowsT fp32 transpose + exact
// numpy-pairwise rn + inits. Per-row serial chain UNCHANGED (bit-exact).
__global__ __launch_bounds__(128)
void convert_hs(const float* __restrict__ hs, ushort_t* __restrict__ Abf,
                float* __restrict__ rn, u32* __restrict__ rowmin,
                float* __restrict__ out, float* __restrict__ rowsT) {
    __shared__ uint4 tile[2][64 * 17];   // per-half bf16 tile; stride 17
    __shared__ float ftile[2][64][129];  // per-half fp32 tile; stride 129 (bank-clean)
    __shared__ float hsx[2][64];
    const int t = threadIdx.x;
    const int tr = t & 63;               // row within block
    const int h = t >> 6;                // half 0/1 (channel groups 0-127 / 128-255)
    const int row0 = blockIdx.x * 64;
    const int row = row0 + tr;
    if (h == 0) {
        rowmin[row] = 0xFFFFFFFFu;
        if (row == 0) out[LOSS_OFF] = 0.0f;
    }
    const int b = row >> 10, hw = row & 1023;
    const float* p = hs + (size_t)b * CHW + hw;
    uint4* Abf4 = reinterpret_cast<uint4*>(Abf);

    float r[8];
    for (int i = 0; i < 128; i += 8) {
        ushort_t pk[8];
        #pragma unroll
        for (int j = 0; j < 8; ++j) {
            int c = h * 128 + i + j;
            float v = p[(size_t)c * HW];       // coalesced across each group's 64 lanes
            pk[j] = bf16bits(v);
            ftile[h][tr][i + j] = v;           // exact fp32 copy for rowsT
            float sq = __fmul_rn(v, v);
            r[j] = (i == 0) ? sq : __fadd_rn(r[j], sq);
        }
        uint4 o;
        o.x = (u32)pk[0] | ((u32)pk[1] << 16);
        o.y = (u32)pk[2] | ((u32)pk[3] << 16);
        o.z = (u32)pk[4] | ((u32)pk[5] << 16);
        o.w = (u32)pk[6] | ((u32)pk[7] << 16);
        tile[h][tr * 17 + (i >> 3)] = o;
    }
    float halfsum = __fadd_rn(__fadd_rn(__fadd_rn(r[0], r[1]), __fadd_rn(r[2], r[3])),
                              __fadd_rn(__fadd_rn(r[4], r[5]), __fadd_rn(r[6], r[7])));
    hsx[h][tr] = halfsum;
    __syncthreads();

    // bf16 store pass: each group writes its own half's 16 uint4 k-slots.
    #pragma unroll
    for (int pass = 0; pass < 16; ++pass) {
        int rr = pass * 4 + (tr >> 4);
        int uh = tr & 15;
        uint4 v = tile[h][rr * 17 + uh];
        int orow = row0 + rr;
        int u = h * 16 + uh;                  // global uint4 k-slot 0..31
        int g = u >> 3;
        int slot = (u & 7) ^ (orow & 7);
        Abf4[(size_t)g * 131072 + (size_t)orow * 8 + slot] = v;
    }

    // fp32 transpose store pass: coalesced 256B rows of rowsT.
    #pragma unroll 8
    for (int i = 0; i < 128; ++i) {
        int rr = i >> 1;
        int cc = ((i & 1) << 6) + tr;
        rowsT[(size_t)(row0 + rr) * 256 + (h << 7) + cc] = ftile[h][rr][cc];
    }
    if (h == 0) rn[row] = __fadd_rn(hsx[0][tr], hsx[1][tr]);
}

// codebook -> bf16, plane-major swizzled. One thread per output uint4 (coalesced).
__global__ __launch_bounds__(256)
void convert_cb(const float* __restrict__ cb, ushort_t* __restrict__ Bbf) {
    int o = blockIdx.x * 256 + threadIdx.x;        // output uint4 idx, 262144 total
    int g = o >> 16;                               // 65536 uint4 per plane
    int rem = o & 65535;
    int code = rem >> 3;
    int slot = rem & 7;
    int u = slot ^ (code & 7);                     // source uint4-in-group
    const float4* src = reinterpret_cast<const float4*>(
        cb + (size_t)code * DIM + (size_t)(g * 8 + u) * 8);
    float4 v0 = src[0], v1 = src[1];
    uint4 out_v;
    out_v.x = (u32)bf16bits(v0.x) | ((u32)bf16bits(v0.y) << 16);
    out_v.y = (u32)bf16bits(v0.z) | ((u32)bf16bits(v0.w) << 16);
    out_v.z = (u32)bf16bits(v1.x) | ((u32)bf16bits(v1.y) << 16);
    out_v.w = (u32)bf16bits(v1.z) | ((u32)bf16bits(v1.w) << 16);
    reinterpret_cast<uint4*>(Bbf)[o] = out_v;
}

// Approx GEMM (round-20 structure, 90.7us verified) with round-22 epilogue:
//   per-ct DPP16 trees -> 16-CODE group mins, packed 4x bf16, one 8-B store
//   per (rt,reg) from lane m==0. rowmin value bit-identical (fp max/min exact,
//   associative). Finer gate granularity halves rescore's filter scan.
__global__ __launch_bounds__(256, 4)
void mfma_approx(const ushort_t* __restrict__ Abf, const ushort_t* __restrict__ Bbf,
                 ushort_t* __restrict__ sbmin16b, u32* __restrict__ rowmin) {
    __shared__ uint4 As4[1024];   // 16 KB: [row 0..127][slot 0..7]
    __shared__ uint4 Bs4[1024];   // 16 KB: [code 0..127][slot 0..7]

    const int tid = threadIdx.x;
    const int n0 = blockIdx.x << 7;     // 128 rows per block
    const int c0 = blockIdx.y << 7;     // 128 codes per block
    const int w = tid >> 6, L = tid & 63;
    const int wr = w & 1, wc = w >> 1;  // wave tile: rows 64*wr, codes 64*wc
    const int m = L & 15, q = L >> 4;
    const uint4* gA = reinterpret_cast<const uint4*>(Abf);
    const uint4* gB = reinterpret_cast<const uint4*>(Bbf);

    accf acc[4][4];
    #pragma unroll
    for (int rt = 0; rt < 4; ++rt)
        #pragma unroll
        for (int ct = 0; ct < 4; ++ct) acc[rt][ct] = (accf){0.f, 0.f, 0.f, 0.f};

#define STAGE(gg) do {                                                        \
    _Pragma("unroll")                                                         \
    for (int r_ = 0; r_ < 4; ++r_) {                                          \
        int j_ = (r_ << 8) + tid;                                             \
        async_cp16(gA + ((size_t)(gg) * 131072 + (size_t)n0 * 8 + j_),        \
                   &As4[j_]);                                                 \
    }                                                                         \
    _Pragma("unroll")                                                         \
    for (int r_ = 0; r_ < 4; ++r_) {                                          \
        int j_ = (r_ << 8) + tid;                                             \
        async_cp16(gB + ((size_t)(gg) * 65536 + (size_t)c0 * 8 + j_),         \
                   &Bs4[j_]);                                                 \
    }                                                                         \
} while (0)

    #pragma unroll
    for (int g = 0; g < 4; ++g) {       // kc = 64*g
        STAGE(g);
        __syncthreads();                // drains stage (vmcnt 0) + publish
        #pragma unroll
        for (int ks = 0; ks < 2; ++ks) {
            const int us = ((ks << 2) + q) ^ (m & 7);
            frag a[4];
            #pragma unroll
            for (int rt = 0; rt < 4; ++rt)
                a[rt] = *reinterpret_cast<const frag*>(
                    &As4[((wr << 6) + (rt << 4) + m) * 8 + us]);
            #pragma unroll
            for (int ct = 0; ct < 4; ++ct) {
                frag bfr = *reinterpret_cast<const frag*>(
                    &Bs4[((wc << 6) + (ct << 4) + m) * 8 + us]);
                #pragma unroll
                for (int rt = 0; rt < 4; ++rt)
                    acc[rt][ct] = __builtin_amdgcn_mfma_f32_16x16x32_bf16(a[rt], bfr, acc[rt][ct], 0, 0, 0);
            }
        }
        if (g < 3) __syncthreads();     // WAR: all reads done before next STAGE
    }
#undef STAGE

    // Epilogue: 16-code group mins (bf16-packed) + row min via DPP.
    const int gbase = (blockIdx.y << 3) + (wc << 2);   // group idx within row's 512
    #pragma unroll
    for (int rt = 0; rt < 4; ++rt) {
        #pragma unroll
        for (int reg = 0; reg < 4; ++reg) {
            float g16[4];
            #pragma unroll
            for (int ct = 0; ct < 4; ++ct)
                g16[ct] = max_dpp16(acc[rt][ct][reg]);
            if (m == 0) {   // lanes 0,16,32,48 (one per 16-lane row)
                int row = n0 + (wr << 6) + (rt << 4) + (q << 2) + reg;
                float mn[4];
                #pragma unroll
                for (int ct = 0; ct < 4; ++ct) mn[ct] = -2.0f * g16[ct];
                u32 p0 = (u32)bf16bits(mn[0]) | ((u32)bf16bits(mn[1]) << 16);
                u32 p1 = (u32)bf16bits(mn[2]) | ((u32)bf16bits(mn[3]) << 16);
                *reinterpret_cast<uint2*>(&sbmin16b[(size_t)row * 512 + gbase]) =
                    make_uint2(p0, p1);
                float m4 = fminf(fminf(mn[0], mn[1]), fminf(mn[2], mn[3]));
                atomicMin(&rowmin[row], forder(m4));
            }
        }
    }
}

// Exact rescore, round-22: gate on 16-code bf16 group mins (+SB_EPS slack,
// superset-safe), then the round-14 wave-cooperative per-code bf16 filter
// (8 lanes per code, one 8-code pass per half-group), survivors -> EXACT
// chain (bit-identical, unchanged).
__global__ __launch_bounds__(64, 4)
void rescore(const float* __restrict__ rowsT, const float* __restrict__ cb,
             const float* __restrict__ rn, const ushort_t* __restrict__ sbmin16b,
             const u32* __restrict__ rowmin, u64* __restrict__ keys,
             const ushort_t* __restrict__ Bbf) {
    __shared__ __align__(16) float fs[256];
    __shared__ int list[512];
    __shared__ int surv[512];
    __shared__ int cnt, cnt2;
    const int bid = blockIdx.x;
    const int row = ((bid & 7) << 11) + (bid >> 3);   // XCD-locality swizzle (r11)
    const int l = threadIdx.x;
    if (l == 0) { cnt = 0; cnt2 = 0; }
    const float4* rT = reinterpret_cast<const float4*>(rowsT + ((size_t)row << 8));
    *reinterpret_cast<float4*>(&fs[l << 2]) = rT[l];   // 64 lanes x 16B = full row
    __syncthreads();

    float thr = unforder(rowmin[row]) + TAU;
    const ushort_t* sb16 = sbmin16b + (size_t)row * 512;
    #pragma unroll
    for (int j = 0; j < 8; ++j) {
        int s = l + 64 * j;                      // 16-code group id 0..511
        float v = bflo((u32)sb16[s]);
        if (v <= thr + SB_EPS) {
            int pos = atomicAdd(&cnt, 1);
            list[pos] = s;
        }
    }
    __syncthreads();
    const int C = cnt;
    const float rn_row = rn[row];
    const uint4* gB4 = reinterpret_cast<const uint4*>(Bbf);
    u64 best = ~0ull;

    // Register-stage this lane's fs slice: k in [32*kp, 32*kp+32).
    const int cid = l >> 3, kp = l & 7;
    float4 freg4[8];
    #pragma unroll
    for (int j = 0; j < 8; ++j)
        freg4[j] = *reinterpret_cast<const float4*>(&fs[kp * 32 + 4 * j]);

    // Cooperative filter: 8 codes per pass; 2 passes per qualifying 16-group.
    const uint4* gBp = gB4 + (size_t)(kp >> 1) * 65536;   // this lane's plane
    for (int it = 0; it < C * 2; ++it) {
        int s = list[it >> 1];
        int by_ = s >> 3, r_ = s & 7;
        int wc_ = r_ >> 2, ct_ = r_ & 3;
        int code = by_ * 128 + wc_ * 64 + ct_ * 16 + (it & 1) * 8 + cid;
        const int cx = code & 7, cbase8 = code << 3;
        uint4 bv[4];
        #pragma unroll
        for (int j = 0; j < 4; ++j) {
            int u = ((kp & 1) << 2) + j;          // uint4-in-plane-group
            bv[j] = gBp[cbase8 + (u ^ cx)];
        }
        float f0 = 0.f, f1 = 0.f, f2 = 0.f, f3 = 0.f;
        #pragma unroll
        for (int j = 0; j < 4; ++j) {
            float4 fa = freg4[2 * j];
            float4 fb = freg4[2 * j + 1];
            f0 = fmaf(fa.x, bflo(bv[j].x), f0);
            f1 = fmaf(fa.y, bfhi(bv[j].x), f1);
            f2 = fmaf(fa.z, bflo(bv[j].y), f2);
            f3 = fmaf(fa.w, bfhi(bv[j].y), f3);
            f0 = fmaf(fb.x, bflo(bv[j].z), f0);
            f1 = fmaf(fb.y, bfhi(bv[j].z), f1);
            f2 = fmaf(fb.z, bflo(bv[j].w), f2);
            f3 = fmaf(fb.w, bfhi(bv[j].w), f3);
        }
        float f = (f0 + f1) + (f2 + f3);
        f += __shfl_xor(f, 1, 64);
        f += __shfl_xor(f, 2, 64);
        f += __shfl_xor(f, 4, 64);
        if (kp == 0 && -2.0f * f <= thr) {
            int pos = atomicAdd(&cnt2, 1);
            if (pos < 512) surv[pos] = code;
            else {                                 // overflow: inline exact (rare)
                u64 key = exact_key(cb, fs, rn_row, code);
                if (key < best) best = key;
            }
        }
    }
    __syncthreads();
    const int S = (cnt2 < 512) ? cnt2 : 512;
    for (int s0 = l; s0 < S; s0 += 64) {
        u64 key = exact_key(cb, fs, rn_row, surv[s0]);
        if (key < best) best = key;
    }
    #pragma unroll
    for (int sh = 1; sh < 64; sh <<= 1) {
        u64 o = __shfl_xor(best, sh, 64);
        if (o < best) best = o;
    }
    if (l == 0) keys[row] = best;
}

// Gather, round-22: x staged from rowsT (coalesced 1-KB rows -> LDS) instead
// of 128-B-segment strided hs reads. Values bit-exact (rowsT is an exact fp32
// copy); output writes and loss arithmetic unchanged.
__global__ __launch_bounds__(256)
void gather_kernel(const float* __restrict__ rowsT, const float* __restrict__ cb,
                   const u64* __restrict__ keys, float* __restrict__ out) {
    __shared__ int codes_s[32];
    __shared__ float q_s[32][257];
    __shared__ float xs[32][257];
    __shared__ float red[4];
    const int g = blockIdx.x;
    const int b = g >> 5;
    const int hw0 = (g & 31) << 5;
    const int t = threadIdx.x;
    const int nbase = b * HW + hw0;

    if (t < 32) {
        int code = (int)(keys[nbase + t] & 0xFFFFFFFFULL);
        codes_s[t] = code;
        out[IDX_OFF + nbase + t] = (float)code;
    }

    // stage x rows (coalesced): row r = t>>3, 8 float4 per thread.
    {
        const int r = t >> 3, f4 = t & 7;
        const float4* xrow = reinterpret_cast<const float4*>(
            rowsT + (size_t)(nbase + r) * 256);
        #pragma unroll
        for (int j = 0; j < 8; ++j) {
            float4 v = xrow[f4 + 8 * j];
            *reinterpret_cast<float4*>(&xs[r][4 * (f4 + 8 * j)]) = v;
        }
    }
    __syncthreads();

    const int r = t >> 3, f4 = t & 7;
    const float4* crow = reinterpret_cast<const float4*>(cb + (size_t)codes_s[r] * DIM);
    #pragma unroll
    for (int j = 0; j < 8; ++j) {
        float4 v = crow[f4 + 8 * j];
        *reinterpret_cast<float4*>(&q_s[r][4 * (f4 + 8 * j)]) = v;
    }
    __syncthreads();

    float d2 = 0.0f;
    const int hw = t & 31, cof = t >> 5;   // 8 c-lanes
    #pragma unroll 8
    for (int it = 0; it < 32; ++it) {
        int c = it * 8 + cof;
        size_t off = (size_t)b * CHW + (size_t)c * HW + hw0 + hw;
        float x = xs[hw][c];
        float qv = q_s[hw][c];
        out[off] = x + (qv - x);           // straight-through forward, exact formula
        float d = qv - x;
        d2 = fmaf(d, d, d2);
    }
    #pragma unroll
    for (int sh = 32; sh >= 1; sh >>= 1) d2 += __shfl_xor(d2, sh, 64);
    if ((t & 63) == 0) red[t >> 6] = d2;
    __syncthreads();
    if (t == 0) {
        float tot = red[0] + red[1] + red[2] + red[3];
        atomicAdd(out + LOSS_OFF, tot * (1.25f / 4194304.0f));  // (1+0.25)*mean
    }
}

extern "C" void kernel_launch(void* const* d_in, const int* in_sizes, int n_in,
                              void* d_out, int out_size, void* d_ws, size_t ws_size,
                              hipStream_t stream) {
    const float* hs = (const float*)d_in[0];   // (16,256,32,32) f32
    const float* cb = (const float*)d_in[1];   // (8192,256) f32
    float* out = (float*)d_out;
    char* ws = (char*)d_ws;
    u64*      keys     = (u64*)(ws + 0);
    float*    rn       = (float*)(ws + 131072);
    u32*      rowmin   = (u32*)(ws + 196608);
    ushort_t* Abf      = (ushort_t*)(ws + 262144);
    ushort_t* Bbf      = (ushort_t*)(ws + 8650752);
    ushort_t* sbmin16b = (ushort_t*)(ws + 12845056);
    float*    rowsT    = (float*)(ws + 29622272);

    convert_hs<<<NROWS / 64, 128, 0, stream>>>(hs, Abf, rn, rowmin, out, rowsT);
    convert_cb<<<1024, 256, 0, stream>>>(cb, Bbf);
    mfma_approx<<<dim3(NROWS / 128, KCODES / 128), 256, 0, stream>>>(Abf, Bbf, sbmin16b, rowmin);
    rescore<<<NROWS, 64, 0, stream>>>(rowsT, cb, rn, sbmin16b, rowmin, keys, Bbf);
    gather_kernel<<<512, 256, 0, stream>>>(rowsT, cb, keys, out);
}

// Round 13
// 244.627 us; speedup vs baseline: 1.0799x; 1.0799x over previous
//
#include <hip/hip_runtime.h>
#include <hip/hip_bf16.h>
#include <stdint.h>

#define NROWS 16384            // 16*32*32 flattened rows
#define KCODES 8192
#define DIM 256
#define HW 1024                // 32*32
#define CHW (DIM*HW)           // 262144
#define IDX_OFF 4194304        // 16*256*32*32
#define LOSS_OFF 4210688       // IDX_OFF + 16384
#define TAU 1.2e-4f            // candidate margin: grid(3.05e-5) + 2*bf16 tail + safety

typedef unsigned long long u64;
typedef unsigned int u32;
typedef unsigned short ushort_t;

using frag = __attribute__((ext_vector_type(8))) short;   // 8 bf16 (4 VGPRs)
using accf = __attribute__((ext_vector_type(4))) float;   // 4 fp32 acc

__device__ __forceinline__ u32 forder(float f) {
    u32 u = __float_as_uint(f);
    return (u & 0x80000000u) ? ~u : (u | 0x80000000u);
}
__device__ __forceinline__ float unforder(u32 v) {
    u32 u = (v & 0x80000000u) ? (v ^ 0x80000000u) : ~v;
    return __uint_as_float(u);
}
__device__ __forceinline__ ushort_t bf16bits(float v) {
    __hip_bfloat16 t = __float2bfloat16(v);   // RNE
    return *reinterpret_cast<ushort_t*>(&t);
}
__device__ __forceinline__ float bflo(u32 u) { return __uint_as_float(u << 16); }
__device__ __forceinline__ float bfhi(u32 u) { return __uint_as_float(u & 0xFFFF0000u); }
__device__ __forceinline__ void async_cp16(const uint4* gp, uint4* lp) {
    __builtin_amdgcn_global_load_lds(
        (const __attribute__((address_space(1))) unsigned int*)gp,
        (__attribute__((address_space(3))) unsigned int*)lp, 16, 0, 0);
}

// max across each 16-lane DPP row, all on the VALU pipe (no DS traffic).
__device__ __forceinline__ float max_dpp16(float v) {
    int x;
    x = __builtin_amdgcn_update_dpp(__float_as_int(v), __float_as_int(v), 0xB1, 0xF, 0xF, true);
    v = fmaxf(v, __int_as_float(x));
    x = __builtin_amdgcn_update_dpp(__float_as_int(v), __float_as_int(v), 0x4E, 0xF, 0xF, true);
    v = fmaxf(v, __int_as_float(x));
    x = __builtin_amdgcn_update_dpp(__float_as_int(v), __float_as_int(v), 0x124, 0xF, 0xF, true);
    v = fmaxf(v, __int_as_float(x));
    x = __builtin_amdgcn_update_dpp(__float_as_int(v), __float_as_int(v), 0x128, 0xF, 0xF, true);
    v = fmaxf(v, __int_as_float(x));
    return v;
}

// EXACT scoring chain (bit-identical to all passing rounds): sequential k fp32
// fmaf on fp32 cb, fl32(rn - 2*dot), key = (ordered score, code); ties -> lowest.
__device__ __forceinline__ u64 exact_key(const float* __restrict__ cb,
                                         const float* __restrict__ fs,
                                         float rn_row, int code) {
    const float4* e4 = reinterpret_cast<const float4*>(&cb[(size_t)code << 8]);
    float acc = 0.0f;
    #pragma unroll 16
    for (int kk = 0; kk < 64; ++kk) {
        float4 ev = e4[kk];
        float4 fv = *reinterpret_cast<const float4*>(&fs[kk << 2]);
        acc = fmaf(fv.x, ev.x, acc);
        acc = fmaf(fv.y, ev.y, acc);
        acc = fmaf(fv.z, ev.z, acc);
        acc = fmaf(fv.w, ev.w, acc);
    }
    float s = __fadd_rn(rn_row, -2.0f * acc);
    return ((u64)forder(s) << 32) | (u64)code;
}

// ws layout (bytes):
//   keys   u64[16384]          @ 0        (131072)
//   rn     f32[16384]          @ 131072   (65536)
//   rowmin u32[16384]          @ 196608   (65536)
//   A_bf   u16[16384*256]      @ 262144   (8388608)  PLANE-MAJOR+SWIZZLED:
//          uint4 idx = g*131072 + row*8 + ((u&7)^(row&7)), g=k-group(64k), u=k/8
//   B_bf   u16[8192*256]       @ 8650752  (4194304)  uint4 idx = g*65536 + code*8 + slot,
//          slot = u ^ (code&7)
//   sbmin  f32[16384*256]      @ 12845056 (16777216) per (row, 32-code sub) approx min
//   rowsT  f32[16384*256]      @ 29622272 (16777216) row-major exact fp32 hs rows

// hs -> bf16 rows (plane-major swizzled) + rowsT fp32 transpose + exact
// numpy-pairwise rn + inits. Per-row serial chain UNCHANGED (bit-exact).
__global__ __launch_bounds__(128)
void convert_hs(const float* __restrict__ hs, ushort_t* __restrict__ Abf,
                float* __restrict__ rn, u32* __restrict__ rowmin,
                float* __restrict__ out, float* __restrict__ rowsT) {
    __shared__ uint4 tile[2][64 * 17];   // per-half bf16 tile; stride 17
    __shared__ float ftile[2][64][129];  // per-half fp32 tile; stride 129 (bank-clean)
    __shared__ float hsx[2][64];
    const int t = threadIdx.x;
    const int tr = t & 63;               // row within block
    const int h = t >> 6;                // half 0/1 (channel groups 0-127 / 128-255)
    const int row0 = blockIdx.x * 64;
    const int row = row0 + tr;
    if (h == 0) {
        rowmin[row] = 0xFFFFFFFFu;
        if (row == 0) out[LOSS_OFF] = 0.0f;
    }
    const int b = row >> 10, hw = row & 1023;
    const float* p = hs + (size_t)b * CHW + hw;
    uint4* Abf4 = reinterpret_cast<uint4*>(Abf);

    float r[8];
    for (int i = 0; i < 128; i += 8) {
        ushort_t pk[8];
        #pragma unroll
        for (int j = 0; j < 8; ++j) {
            int c = h * 128 + i + j;
            float v = p[(size_t)c * HW];       // coalesced across each group's 64 lanes
            pk[j] = bf16bits(v);
            ftile[h][tr][i + j] = v;           // exact fp32 copy for rowsT
            float sq = __fmul_rn(v, v);
            r[j] = (i == 0) ? sq : __fadd_rn(r[j], sq);
        }
        uint4 o;
        o.x = (u32)pk[0] | ((u32)pk[1] << 16);
        o.y = (u32)pk[2] | ((u32)pk[3] << 16);
        o.z = (u32)pk[4] | ((u32)pk[5] << 16);
        o.w = (u32)pk[6] | ((u32)pk[7] << 16);
        tile[h][tr * 17 + (i >> 3)] = o;
    }
    float halfsum = __fadd_rn(__fadd_rn(__fadd_rn(r[0], r[1]), __fadd_rn(r[2], r[3])),
                              __fadd_rn(__fadd_rn(r[4], r[5]), __fadd_rn(r[6], r[7])));
    hsx[h][tr] = halfsum;
    __syncthreads();

    // bf16 store pass: each group writes its own half's 16 uint4 k-slots.
    #pragma unroll
    for (int pass = 0; pass < 16; ++pass) {
        int rr = pass * 4 + (tr >> 4);
        int uh = tr & 15;
        uint4 v = tile[h][rr * 17 + uh];
        int orow = row0 + rr;
        int u = h * 16 + uh;                  // global uint4 k-slot 0..31
        int g = u >> 3;
        int slot = (u & 7) ^ (orow & 7);
        Abf4[(size_t)g * 131072 + (size_t)orow * 8 + slot] = v;
    }

    // fp32 transpose store pass: coalesced 256B rows of rowsT.
    #pragma unroll 8
    for (int i = 0; i < 128; ++i) {
        int rr = i >> 1;
        int cc = ((i & 1) << 6) + tr;
        rowsT[(size_t)(row0 + rr) * 256 + (h << 7) + cc] = ftile[h][rr][cc];
    }
    if (h == 0) rn[row] = __fadd_rn(hsx[0][tr], hsx[1][tr]);
}

// codebook -> bf16, plane-major swizzled. One thread per output uint4 (coalesced).
__global__ __launch_bounds__(256)
void convert_cb(const float* __restrict__ cb, ushort_t* __restrict__ Bbf) {
    int o = blockIdx.x * 256 + threadIdx.x;        // output uint4 idx, 262144 total
    int g = o >> 16;                               // 65536 uint4 per plane
    int rem = o & 65535;
    int code = rem >> 3;
    int slot = rem & 7;
    int u = slot ^ (code & 7);                     // source uint4-in-group
    const float4* src = reinterpret_cast<const float4*>(
        cb + (size_t)code * DIM + (size_t)(g * 8 + u) * 8);
    float4 v0 = src[0], v1 = src[1];
    uint4 out_v;
    out_v.x = (u32)bf16bits(v0.x) | ((u32)bf16bits(v0.y) << 16);
    out_v.y = (u32)bf16bits(v0.z) | ((u32)bf16bits(v0.w) << 16);
    out_v.z = (u32)bf16bits(v1.x) | ((u32)bf16bits(v1.y) << 16);
    out_v.w = (u32)bf16bits(v1.z) | ((u32)bf16bits(v1.w) << 16);
    reinterpret_cast<uint4*>(Bbf)[o] = out_v;
}

// Approx GEMM (round-20 structure, 90.7us verified). Round-24: split into 4
// dispatches over blockIdx.y quarters for PROFILER VISIBILITY. KCODES/128 = 64
// y-tiles total -> y0 in {0,16,32,48}, 16 y-blocks per dispatch (r12's bug was
// covering only 32 of 64 y-tiles). rowmin is a device-scope atomic
// (cross-dispatch safe on one stream); sbmin slices are disjoint per quarter.
__global__ __launch_bounds__(256, 4)
void mfma_approx(const ushort_t* __restrict__ Abf, const ushort_t* __restrict__ Bbf,
                 float* __restrict__ sbmin, u32* __restrict__ rowmin, int y0) {
    __shared__ uint4 As4[1024];   // 16 KB: [row 0..127][slot 0..7]
    __shared__ uint4 Bs4[1024];   // 16 KB: [code 0..127][slot 0..7]

    const int tid = threadIdx.x;
    const int by = y0 + blockIdx.y;
    const int n0 = blockIdx.x << 7;     // 128 rows per block
    const int c0 = by << 7;             // 128 codes per block
    const int w = tid >> 6, L = tid & 63;
    const int wr = w & 1, wc = w >> 1;  // wave tile: rows 64*wr, codes 64*wc
    const int m = L & 15, q = L >> 4;
    const uint4* gA = reinterpret_cast<const uint4*>(Abf);
    const uint4* gB = reinterpret_cast<const uint4*>(Bbf);

    accf acc[4][4];
    #pragma unroll
    for (int rt = 0; rt < 4; ++rt)
        #pragma unroll
        for (int ct = 0; ct < 4; ++ct) acc[rt][ct] = (accf){0.f, 0.f, 0.f, 0.f};

#define STAGE(gg) do {                                                        \
    _Pragma("unroll")                                                         \
    for (int r_ = 0; r_ < 4; ++r_) {                                          \
        int j_ = (r_ << 8) + tid;                                             \
        async_cp16(gA + ((size_t)(gg) * 131072 + (size_t)n0 * 8 + j_),        \
                   &As4[j_]);                                                 \
    }                                                                         \
    _Pragma("unroll")                                                         \
    for (int r_ = 0; r_ < 4; ++r_) {                                          \
        int j_ = (r_ << 8) + tid;                                             \
        async_cp16(gB + ((size_t)(gg) * 65536 + (size_t)c0 * 8 + j_),         \
                   &Bs4[j_]);                                                 \
    }                                                                         \
} while (0)

    #pragma unroll
    for (int g = 0; g < 4; ++g) {       // kc = 64*g
        STAGE(g);
        __syncthreads();                // drains stage (vmcnt 0) + publish
        #pragma unroll
        for (int ks = 0; ks < 2; ++ks) {
            const int us = ((ks << 2) + q) ^ (m & 7);
            frag a[4];
            #pragma unroll
            for (int rt = 0; rt < 4; ++rt)
                a[rt] = *reinterpret_cast<const frag*>(
                    &As4[((wr << 6) + (rt << 4) + m) * 8 + us]);
            #pragma unroll
            for (int ct = 0; ct < 4; ++ct) {
                frag bfr = *reinterpret_cast<const frag*>(
                    &Bs4[((wc << 6) + (ct << 4) + m) * 8 + us]);
                #pragma unroll
                for (int rt = 0; rt < 4; ++rt)
                    acc[rt][ct] = __builtin_amdgcn_mfma_f32_16x16x32_bf16(a[rt], bfr, acc[rt][ct], 0, 0, 0);
            }
        }
        if (g < 3) __syncthreads();     // WAR: all reads done before next STAGE
    }
#undef STAGE

    // Epilogue (r20-verified): subblock (32-code) mins + row min via DPP.
    const int cbase = (by << 2) + (wc << 1);
    #pragma unroll
    for (int rt = 0; rt < 4; ++rt) {
        #pragma unroll
        for (int reg = 0; reg < 4; ++reg) {
            float mx[2];
            #pragma unroll
            for (int p = 0; p < 2; ++p)
                mx[p] = fmaxf(acc[rt][2 * p][reg], acc[rt][2 * p + 1][reg]);
            #pragma unroll
            for (int p = 0; p < 2; ++p) mx[p] = max_dpp16(mx[p]);
            if (m == 0) {   // lanes 0,16,32,48 (one per 16-lane row)
                int row = n0 + (wr << 6) + (rt << 4) + (q << 2) + reg;
                float mn[2];
                #pragma unroll
                for (int p = 0; p < 2; ++p) {
                    mn[p] = -2.0f * mx[p];
                    sbmin[(size_t)row * 256 + cbase + p] = mn[p];
                }
                float m2 = fminf(mn[0], mn[1]);
                atomicMin(&rowmin[row], forder(m2));
            }
        }
    }
}

// Exact rescore (round-21 state, verified in the 243.3us best round): r14
// wave-cooperative filter + rowsT coalesced fs-fill. Survivors -> EXACT chain.
__global__ __launch_bounds__(64, 4)
void rescore(const float* __restrict__ rowsT, const float* __restrict__ cb,
             const float* __restrict__ rn, const float* __restrict__ sbmin,
             const u32* __restrict__ rowmin, u64* __restrict__ keys,
             const ushort_t* __restrict__ Bbf) {
    __shared__ __align__(16) float fs[256];
    __shared__ int list[256];
    __shared__ int surv[512];
    __shared__ int cnt, cnt2;
    const int bid = blockIdx.x;
    const int row = ((bid & 7) << 11) + (bid >> 3);   // XCD-locality swizzle (r11)
    const int l = threadIdx.x;
    if (l == 0) { cnt = 0; cnt2 = 0; }
    const float4* rT = reinterpret_cast<const float4*>(rowsT + ((size_t)row << 8));
    *reinterpret_cast<float4*>(&fs[l << 2]) = rT[l];   // 64 lanes x 16B = full row
    __syncthreads();

    float thr = unforder(rowmin[row]) + TAU;
    #pragma unroll
    for (int j = 0; j < 4; ++j) {
        int sb = l + 64 * j;
        if (sbmin[(size_t)row * 256 + sb] <= thr) {
            int pos = atomicAdd(&cnt, 1);
            list[pos] = sb;
        }
    }
    __syncthreads();
    const int C = cnt;
    const float rn_row = rn[row];
    const uint4* gB4 = reinterpret_cast<const uint4*>(Bbf);
    u64 best = ~0ull;

    // Register-stage this lane's fs slice: k in [32*kp, 32*kp+32).
    const int cid = l >> 3, kp = l & 7;
    float4 freg4[8];
    #pragma unroll
    for (int j = 0; j < 8; ++j)
        freg4[j] = *reinterpret_cast<const float4*>(&fs[kp * 32 + 4 * j]);

    // Cooperative filter: 8 codes per pass (one subblock = 4 passes).
    const uint4* gBp = gB4 + (size_t)(kp >> 1) * 65536;   // this lane's plane
    for (int it = 0; it < C * 4; ++it) {
        int code = list[it >> 2] * 32 + (it & 3) * 8 + cid;
        const int cx = code & 7, cbase8 = code << 3;
        uint4 bv[4];
        #pragma unroll
        for (int j = 0; j < 4; ++j) {
            int u = ((kp & 1) << 2) + j;          // uint4-in-plane-group
            bv[j] = gBp[cbase8 + (u ^ cx)];
        }
        float f0 = 0.f, f1 = 0.f, f2 = 0.f, f3 = 0.f;
        #pragma unroll
        for (int j = 0; j < 4; ++j) {
            float4 fa = freg4[2 * j];
            float4 fb = freg4[2 * j + 1];
            f0 = fmaf(fa.x, bflo(bv[j].x), f0);
            f1 = fmaf(fa.y, bfhi(bv[j].x), f1);
            f2 = fmaf(fa.z, bflo(bv[j].y), f2);
            f3 = fmaf(fa.w, bfhi(bv[j].y), f3);
            f0 = fmaf(fb.x, bflo(bv[j].z), f0);
            f1 = fmaf(fb.y, bfhi(bv[j].z), f1);
            f2 = fmaf(fb.z, bflo(bv[j].w), f2);
            f3 = fmaf(fb.w, bfhi(bv[j].w), f3);
        }
        float f = (f0 + f1) + (f2 + f3);
        f += __shfl_xor(f, 1, 64);
        f += __shfl_xor(f, 2, 64);
        f += __shfl_xor(f, 4, 64);
        if (kp == 0 && -2.0f * f <= thr) {
            int pos = atomicAdd(&cnt2, 1);
            if (pos < 512) surv[pos] = code;
            else {                                 // overflow: inline exact (rare)
                u64 key = exact_key(cb, fs, rn_row, code);
                if (key < best) best = key;
            }
        }
    }
    __syncthreads();
    const int S = (cnt2 < 512) ? cnt2 : 512;
    for (int s0 = l; s0 < S; s0 += 64) {
        u64 key = exact_key(cb, fs, rn_row, surv[s0]);
        if (key < best) best = key;
    }
    #pragma unroll
    for (int sh = 1; sh < 64; sh <<= 1) {
        u64 o = __shfl_xor(best, sh, 64);
        if (o < best) best = o;
    }
    if (l == 0) keys[row] = best;
}

// Gather (round-21 state, verified in the 243.3us best round): 512 blocks,
// each owns (b, 32-hw chunk) x all 256 c. Values exact: x + (q - x).
__global__ __launch_bounds__(256)
void gather_kernel(const float* __restrict__ hs, const float* __restrict__ cb,
                   const u64* __restrict__ keys, float* __restrict__ out) {
    __shared__ int codes_s[32];
    __shared__ float q_s[32][257];
    __shared__ float red[4];
    const int g = blockIdx.x;
    const int b = g >> 5;
    const int hw0 = (g & 31) << 5;
    const int t = threadIdx.x;
    const int nbase = b * HW + hw0;

    if (t < 32) {
        int code = (int)(keys[nbase + t] & 0xFFFFFFFFULL);
        codes_s[t] = code;
        out[IDX_OFF + nbase + t] = (float)code;
    }
    __syncthreads();

    const int r = t >> 3, f4 = t & 7;
    const float4* crow = reinterpret_cast<const float4*>(cb + (size_t)codes_s[r] * DIM);
    #pragma unroll
    for (int j = 0; j < 8; ++j) {
        float4 v = crow[f4 + 8 * j];
        *reinterpret_cast<float4*>(&q_s[r][4 * (f4 + 8 * j)]) = v;
    }
    __syncthreads();

    float d2 = 0.0f;
    const int hw = t & 31, cof = t >> 5;   // 8 c-lanes
    #pragma unroll 8
    for (int it = 0; it < 32; ++it) {
        int c = it * 8 + cof;
        size_t off = (size_t)b * CHW + (size_t)c * HW + hw0 + hw;
        float x = hs[off];
        float qv = q_s[hw][c];
        out[off] = x + (qv - x);           // straight-through forward, exact formula
        float d = qv - x;
        d2 = fmaf(d, d, d2);
    }
    #pragma unroll
    for (int sh = 32; sh >= 1; sh >>= 1) d2 += __shfl_xor(d2, sh, 64);
    if ((t & 63) == 0) red[t >> 6] = d2;
    __syncthreads();
    if (t == 0) {
        float tot = red[0] + red[1] + red[2] + red[3];
        atomicAdd(out + LOSS_OFF, tot * (1.25f / 4194304.0f));  // (1+0.25)*mean
    }
}

extern "C" void kernel_launch(void* const* d_in, const int* in_sizes, int n_in,
                              void* d_out, int out_size, void* d_ws, size_t ws_size,
                              hipStream_t stream) {
    const float* hs = (const float*)d_in[0];   // (16,256,32,32) f32
    const float* cb = (const float*)d_in[1];   // (8192,256) f32
    float* out = (float*)d_out;
    char* ws = (char*)d_ws;
    u64*      keys   = (u64*)(ws + 0);
    float*    rn     = (float*)(ws + 131072);
    u32*      rowmin = (u32*)(ws + 196608);
    ushort_t* Abf    = (ushort_t*)(ws + 262144);
    ushort_t* Bbf    = (ushort_t*)(ws + 8650752);
    float*    sbmin  = (float*)(ws + 12845056);
    float*    rowsT  = (float*)(ws + 29622272);

    convert_hs<<<NROWS / 64, 128, 0, stream>>>(hs, Abf, rn, rowmin, out, rowsT);
    convert_cb<<<1024, 256, 0, stream>>>(cb, Bbf);
    // 4 quarter-dispatches covering ALL 64 y-tiles (KCODES/128 = 64):
    // y0 in {0,16,32,48}, 16 y-blocks each. Identical total work to the
    // single dispatch; each ~23us -> exposes other kernels in top-5 profile.
    for (int y0 = 0; y0 < 64; y0 += 16)
        mfma_approx<<<dim3(NROWS / 128, 16), 256, 0, stream>>>(Abf, Bbf, sbmin, rowmin, y0);
    rescore<<<NROWS, 64, 0, stream>>>(rowsT, cb, rn, sbmin, rowmin, keys, Bbf);
    gather_kernel<<<512, 256, 0, stream>>>(hs, cb, keys, out);
}